// Round 10
// baseline (504.084 us; speedup 1.0000x reference)
//
#include <hip/hip_runtime.h>
#include <math.h>
#include <stdint.h>

#define Bz 4
#define Tz 2048
#define Cz 1024
#define Hz 16
#define Dz 64
#define MTOK (Bz*Tz)   // 8192
#define ATT_SC 0.18033688011112042f   // 0.125 * log2(e) — folded into Q at QKV epilogue

typedef __attribute__((ext_vector_type(8))) short short8;
typedef __attribute__((ext_vector_type(4))) short short4v;
typedef __attribute__((ext_vector_type(4))) float f32x4;

typedef unsigned int u32_g __attribute__((address_space(1)));
typedef unsigned int u32_l __attribute__((address_space(3)));

__device__ __forceinline__ unsigned short f2bf(float f) {
    unsigned int u = __float_as_uint(f);
    u += 0x7fffu + ((u >> 16) & 1u);
    return (unsigned short)(u >> 16);
}
__device__ __forceinline__ float bf2f(unsigned short h) {
    return __uint_as_float((unsigned int)h << 16);
}

__device__ __forceinline__ void async_cp16(const unsigned short* g, unsigned short* l) {
    __builtin_amdgcn_global_load_lds((const u32_g*)g, (u32_l*)l, 16, 0, 0);
}

#define BARX() asm volatile("s_barrier" ::: "memory")
#define VMCM(n) asm volatile("s_waitcnt vmcnt(" #n ")" ::: "memory")
#define LGKMC(n) do { asm volatile("s_waitcnt lgkmcnt(" #n ")" ::: "memory"); \
                      __builtin_amdgcn_sched_barrier(0); } while (0)

// ---- weight prep: W[K][N] f32 -> Bf fragment-ordered bf16 ----------------------
__global__ void transpose_wf(const float* __restrict__ W, unsigned short* __restrict__ Bf,
                             int K, int N) {
    const int nf = blockIdx.x;
    const int k0 = blockIdx.y * 128;
    const int tid = threadIdx.x;          // 256
    const int ktl = tid >> 6, lane = tid & 63;
    const int col = nf * 16 + (lane & 15);
    const int kk = k0 + ktl * 32 + (lane >> 4) * 8;
    const int KT = K >> 5;
    short8 o;
    #pragma unroll
    for (int j = 0; j < 8; j++)
        o[j] = (short)f2bf(W[(size_t)(kk + j) * N + col]);
    *(short8*)&Bf[(((size_t)nf * KT + (k0 >> 5) + ktl) * 64 + lane) * 8] = o;
}

// ---------------- V transpose: vtmp[B*H][T][D] -> vt[B*H][D][T] -----------------
__global__ void transpose_v(const unsigned short* __restrict__ in, unsigned short* __restrict__ out) {
    __shared__ unsigned short tile[64][68];
    const int bh = blockIdx.x;
    const int t0 = blockIdx.y * 64;
    const int tid = threadIdx.x;
    const int r4 = tid >> 4;
    const int c4 = tid & 15;
    #pragma unroll
    for (int p = 0; p < 4; p++) {
        const int r = p * 16 + r4;
        *(short4v*)&tile[r][c4 * 4] =
            *(const short4v*)&in[((size_t)bh * Tz + t0 + r) * Dz + c4 * 4];
    }
    __syncthreads();
    #pragma unroll
    for (int p = 0; p < 4; p++) {
        const int d = p * 16 + r4;
        short4v o;
        #pragma unroll
        for (int j = 0; j < 4; j++) o[j] = tile[c4 * 4 + j][d];
        *(short4v*)&out[((size_t)bh * Dz + d) * Tz + t0 + c4 * 4] = o;
    }
}

// ---------------- layernorm: fp32 in -> bf16 out ----------------
__global__ void ln_kernel(const float* __restrict__ x, const float* __restrict__ g,
                          const float* __restrict__ bb, unsigned short* __restrict__ out) {
    int tok = blockIdx.x, tid = threadIdx.x;
    const float4 v = ((const float4*)(x + (size_t)tok * Cz))[tid];
    float s = v.x + v.y + v.z + v.w;
    float sq = v.x * v.x + v.y * v.y + v.z * v.z + v.w * v.w;
    #pragma unroll
    for (int m = 1; m < 64; m <<= 1) { s += __shfl_xor(s, m); sq += __shfl_xor(sq, m); }
    __shared__ float red[8];
    int lane = tid & 63, wid = tid >> 6;
    if (!lane) { red[wid] = s; red[4 + wid] = sq; }
    __syncthreads();
    s = red[0] + red[1] + red[2] + red[3];
    sq = red[4] + red[5] + red[6] + red[7];
    float mu = s * (1.0f / Cz);
    float var = sq * (1.0f / Cz) - mu * mu;
    float rs = rsqrtf(var + 1e-5f);
    float4 gv = ((const float4*)g)[tid];
    float4 bv = ((const float4*)bb)[tid];
    short4v o;
    o[0] = f2bf((v.x - mu) * rs * gv.x + bv.x);
    o[1] = f2bf((v.y - mu) * rs * gv.y + bv.y);
    o[2] = f2bf((v.z - mu) * rs * gv.z + bv.z);
    o[3] = f2bf((v.w - mu) * rs * gv.w + bv.w);
    *(short4v*)(out + (size_t)tok * Cz + tid * 4) = o;
}

#define MODE_QKV 0
#define MODE_RESID 1
#define MODE_GELU 2

// ========== register-pipelined GEMM: BM=64 x BN=256, BK=32, 256 thr =============
// (frozen from round 9 — measured 28-33% MfmaUtil — except Q pre-scale line)
template <int MODE>
__launch_bounds__(256)
__global__ void gemm_rp(const unsigned short* __restrict__ A, const unsigned short* __restrict__ Bf,
                        int K, int N, const float* __restrict__ bias,
                        float* __restrict__ outf, unsigned short* __restrict__ outb,
                        const float* __restrict__ resid,
                        unsigned short* __restrict__ qo, unsigned short* __restrict__ ko,
                        unsigned short* __restrict__ vo) {
    __shared__ __align__(16) unsigned short LDS[4 * 2048];   // 16 KiB
    const int tid = threadIdx.x;
    const int lane = tid & 63;
    const int gn = tid >> 6;               // wave = n-group 0..3
    const int quad = lane >> 4, l15 = lane & 15;
    const int id = blockIdx.x;
    const int rr = id >> 3;
    const int m0 = ((id & 7) * 16 + (rr & 15)) * 64;  // same-m across n -> same XCD
    const int n0 = (rr >> 4) * 256;
    const int NT = K >> 5;
    const int KT = K >> 5;

    const int lseg = (tid & 3) ^ ((tid >> 3) & 3);
    const int srow = tid >> 2;
    const unsigned short* Ag0 = A + (size_t)(m0 + srow) * K + lseg * 8;

    const unsigned ldsA = (unsigned)(uintptr_t)(u32_l*)LDS;
    unsigned offAb[4];
    #pragma unroll
    for (int mi = 0; mi < 4; mi++) {
        const int ra = mi * 16 + l15;
        offAb[mi] = (unsigned)(ra * 64 + ((quad ^ ((ra >> 1) & 3)) << 4));
    }

    const int nfg = (n0 >> 4) + gn * 4;
    const unsigned short* Bp[4];
    #pragma unroll
    for (int ni = 0; ni < 4; ni++)
        Bp[ni] = Bf + ((size_t)(nfg + ni) * KT) * 512 + lane * 8;

    f32x4 acc[4][4] = {};
    short8 afP[4], afQ[4], bfP[4], bfQ[4];

#define GLBa(bfX) do { _Pragma("unroll") for (int ni = 0; ni < 4; ni++) { \
    asm volatile("global_load_dwordx4 %0, %1, off" \
        : "=&v"(bfX[ni]) : "v"((unsigned long long)(uintptr_t)Bp[ni]) : "memory"); \
    Bp[ni] += 512; } } while (0)
#define STG(tt) async_cp16(Ag0 + (size_t)(tt) * 32, LDS + (((unsigned)(tt)) & 3u) * 2048 + tid * 8)
#define RDSa(afX, tt) do { \
    const unsigned sb_ = ldsA + (((unsigned)(tt)) & 3u) * 4096u; \
    _Pragma("unroll") for (int mi = 0; mi < 4; mi++) \
        asm volatile("ds_read_b128 %0, %1" : "=&v"(afX[mi]) : "v"(sb_ + offAb[mi])); } while (0)
#define MMS(afX, bfX) do { \
    __builtin_amdgcn_s_setprio(1); \
    _Pragma("unroll") for (int mi = 0; mi < 4; mi++) \
        _Pragma("unroll") for (int ni = 0; ni < 4; ni++) \
            acc[mi][ni] = __builtin_amdgcn_mfma_f32_16x16x32_bf16(afX[mi], bfX[ni], acc[mi][ni], 0, 0, 0); \
    __builtin_amdgcn_s_setprio(0); } while (0)

    STG(0); STG(1); GLBa(bfP); GLBa(bfQ); STG(2);
    VMCM(5);
    BARX();
    RDSa(afP, 0);

    for (int t = 0; t < NT; t += 2) {
        if (t + 3 < NT) STG(t + 3);
        RDSa(afQ, t + 1);
        LGKMC(4);
        MMS(afP, bfP);
        if (t + 2 < NT) GLBa(bfP);
        if (t + 3 < NT) { VMCM(5); } else { VMCM(0); }
        BARX();
        if (t + 4 < NT) STG(t + 4);
        if (t + 2 < NT) { RDSa(afP, t + 2); LGKMC(4); } else { LGKMC(0); }
        MMS(afQ, bfQ);
        if (t + 3 < NT) GLBa(bfQ);
        if (t + 4 < NT) { VMCM(5); } else { VMCM(0); }
        BARX();
    }
#undef GLBa
#undef STG
#undef RDSa
#undef MMS

    float bv[4];
    #pragma unroll
    for (int ni = 0; ni < 4; ni++) bv[ni] = bias[n0 + gn * 64 + ni * 16 + l15];

    if constexpr (MODE == MODE_QKV) {
        const int colb = n0 + gn * 64;
        const int which = colb >> 10;
        const int hh = (colb & 1023) >> 6;
        unsigned short* dst = (which == 0) ? qo : (which == 1) ? ko : vo;
        const float qsc = (which == 0) ? ATT_SC : 1.0f;   // pre-scale Q rows (uniform)
        #pragma unroll
        for (int mi = 0; mi < 4; mi++) {
            #pragma unroll
            for (int r = 0; r < 4; r++) {
                const int row = m0 + mi * 16 + quad * 4 + r;
                const int b_ = row >> 11, tt = row & 2047;
                unsigned short* rp = dst + ((size_t)(b_ * Hz + hh) * Tz + tt) * Dz;
                #pragma unroll
                for (int ni = 0; ni < 4; ni++)
                    rp[ni * 16 + l15] = f2bf((acc[mi][ni][r] + bv[ni]) * qsc);
            }
        }
    } else if constexpr (MODE == MODE_RESID) {
        #pragma unroll
        for (int mi = 0; mi < 4; mi++) {
            #pragma unroll
            for (int r = 0; r < 4; r++) {
                const int row = m0 + mi * 16 + quad * 4 + r;
                float* rp = outf + (size_t)row * N + n0 + gn * 64;
                const float* rr_ = resid + (size_t)row * N + n0 + gn * 64;
                #pragma unroll
                for (int ni = 0; ni < 4; ni++) {
                    const int c = ni * 16 + l15;
                    rp[c] = acc[mi][ni][r] + bv[ni] + rr_[c];
                }
            }
        }
    } else {  // MODE_GELU, tanh-form
        #pragma unroll
        for (int mi = 0; mi < 4; mi++) {
            #pragma unroll
            for (int r = 0; r < 4; r++) {
                const int row = m0 + mi * 16 + quad * 4 + r;
                unsigned short* rp = outb + (size_t)row * N + n0 + gn * 64;
                #pragma unroll
                for (int ni = 0; ni < 4; ni++) {
                    float val = acc[mi][ni][r] + bv[ni];
                    float c = val * (1.0f + 0.044715f * val * val);
                    float e = __expf(1.5957691216057308f * c);
                    rp[ni * 16 + l15] = f2bf(val * e / (1.0f + e));
                }
            }
        }
    }
}

// ---------------- causal flash attention, bf16 MFMA ----------------
// This round: (1) Q pre-scaled at QKV epilogue -> no per-element mul;
// (2) P->bf16 via v_cvt_pk_bf16_f32 pairs (8 cvt + 8 shr vs 48 VALU ops);
// (3) K/V chunk double-buffer: stage(ci+1) issued after top barrier, waited at
//     next top (one full compute later -> latency hidden); 1 barrier/chunk,
//     slot-reuse safe because passing barrier of iter ci+1 implies all waves
//     finished reading slot ci.
__launch_bounds__(256)
__global__ void attn_kernel(const unsigned short* __restrict__ qb, const unsigned short* __restrict__ kb,
                            const unsigned short* __restrict__ vt, unsigned short* __restrict__ y) {
    __shared__ __align__(16) unsigned short Klds[2][64 * 64];
    __shared__ __align__(16) unsigned short Vtl[2][64 * 64];
    __shared__ __align__(16) unsigned short Plds[4][16 * 72];
    const int tid = threadIdx.x;
    const int lane = tid & 63, wid = tid >> 6;
    const int quad = lane >> 4, l15 = lane & 15;
    const int bh = blockIdx.x & 63;
    const int qt = 15 - (int)(blockIdx.x >> 6);
    const size_t baseT = (size_t)bh * Tz;
    const size_t vbase = (size_t)bh * Dz;
    const int qb0 = qt * 128;

    const int srow = lane >> 3;
    const int swz = ((lane & 7) ^ srow) * 8;
    const unsigned short* kg0 = kb + (baseT + wid * 8 + srow) * Dz + swz;
    const unsigned short* kg1 = kg0 + (size_t)32 * Dz;
    const unsigned short* vg0 = vt + (vbase + wid * 8 + srow) * Tz + swz;
    const unsigned short* vg1 = vg0 + (size_t)32 * Tz;
    const int lofs = wid * 512 + lane * 8;

#define ASTG(ci_) do { const int s_ = (ci_) & 1; const int kk_ = (ci_) * 64; \
    async_cp16(kg0 + (size_t)kk_ * Dz, &Klds[s_][lofs]); \
    async_cp16(kg1 + (size_t)kk_ * Dz, &Klds[s_][2048 + lofs]); \
    async_cp16(vg0 + kk_, &Vtl[s_][lofs]); \
    async_cp16(vg1 + kk_, &Vtl[s_][2048 + lofs]); } while (0)

    ASTG(0);   // chunk-0 prefetch overlaps the Q loads below

    short8 qf[2][2];
    {
        const unsigned short* q0p = qb + (baseT + qb0 + wid * 16 + l15) * Dz + quad * 8;
        qf[0][0] = *(const short8*)q0p;
        qf[0][1] = *(const short8*)(q0p + 32);
        const unsigned short* q1p = q0p + (size_t)64 * Dz;
        qf[1][0] = *(const short8*)q1p;
        qf[1][1] = *(const short8*)(q1p + 32);
    }

    f32x4 o[2][4] = {};
    float lsum[2][4] = {{0.f,0.f,0.f,0.f},{0.f,0.f,0.f,0.f}};

    const int nchunk = 2 * qt + 2;

    for (int ci = 0; ci < nchunk; ci++) {
        VMCM(0);                         // chunk ci landed (issued one compute earlier)
        BARX();
        if (ci + 1 < nchunk) ASTG(ci + 1);
        const int sl = ci & 1;
        const int k0 = ci * 64;

        #pragma unroll
        for (int t = 0; t < 2; t++) {
            if (t == 0 && ci == nchunk - 1) continue;
            const bool diag = (ci == nchunk - 2 + t);

            f32x4 s[4];
            #pragma unroll
            for (int c = 0; c < 4; c++) {
                const int rk = c * 16 + l15;
                short8 kf0 = *(const short8*)&Klds[sl][rk * 64 + ((quad ^ (rk & 7)) * 8)];
                short8 kf1 = *(const short8*)&Klds[sl][rk * 64 + (((quad + 4) ^ (rk & 7)) * 8)];
                f32x4 z = {};
                z = __builtin_amdgcn_mfma_f32_16x16x32_bf16(qf[t][0], kf0, z, 0, 0, 0);
                s[c] = __builtin_amdgcn_mfma_f32_16x16x32_bf16(qf[t][1], kf1, z, 0, 0, 0);
            }
            const int qr = qb0 + t * 64 + wid * 16 + quad * 4;
            #pragma unroll
            for (int c = 0; c < 4; c++)
                #pragma unroll
                for (int r = 0; r < 4; r++) {
                    float p = exp2f(s[c][r]);          // Q pre-scaled: no mul
                    if (diag) {
                        int key = k0 + c * 16 + l15;
                        p = (key <= qr + r) ? p : 0.f;
                    }
                    s[c][r] = p;
                    lsum[t][r] += p;
                }
            unsigned short* P = Plds[wid];
            #pragma unroll
            for (int c = 0; c < 4; c++) {
                #pragma unroll
                for (int rp2 = 0; rp2 < 2; rp2++) {
                    unsigned pk;
                    asm("v_cvt_pk_bf16_f32 %0, %1, %2"
                        : "=v"(pk) : "v"(s[c][2 * rp2]), "v"(s[c][2 * rp2 + 1]));
                    P[(quad * 4 + 2 * rp2) * 72 + c * 16 + l15] = (unsigned short)pk;
                    P[(quad * 4 + 2 * rp2 + 1) * 72 + c * 16 + l15] = (unsigned short)(pk >> 16);
                }
            }
            short8 pf0 = *(const short8*)&P[l15 * 72 + quad * 8];
            short8 pf1 = *(const short8*)&P[l15 * 72 + 32 + quad * 8];
            #pragma unroll
            for (int nc = 0; nc < 4; nc++) {
                const int rv = nc * 16 + l15;
                short8 vf0 = *(const short8*)&Vtl[sl][rv * 64 + ((quad ^ (rv & 7)) * 8)];
                short8 vf1 = *(const short8*)&Vtl[sl][rv * 64 + (((quad + 4) ^ (rv & 7)) * 8)];
                o[t][nc] = __builtin_amdgcn_mfma_f32_16x16x32_bf16(pf0, vf0, o[t][nc], 0, 0, 0);
                o[t][nc] = __builtin_amdgcn_mfma_f32_16x16x32_bf16(pf1, vf1, o[t][nc], 0, 0, 0);
            }
        }
        // no trailing barrier: next iteration's top barrier protects slot reuse
    }
#undef ASTG

    const int b_ = bh >> 4, hh = bh & 15;
    #pragma unroll
    for (int t = 0; t < 2; t++)
        #pragma unroll
        for (int r = 0; r < 4; r++) {
            float ls = lsum[t][r];
            #pragma unroll
            for (int m = 1; m < 16; m <<= 1) ls += __shfl_xor(ls, m);
            float inv = 1.0f / ls;
            size_t tok = (size_t)qb0 + t * 64 + wid * 16 + quad * 4 + r;
            unsigned short* yr = y + ((size_t)b_ * Tz + tok) * Cz + hh * Dz;
            #pragma unroll
            for (int nc = 0; nc < 4; nc++)
                yr[nc * 16 + l15] = f2bf(o[t][nc][r] * inv);
        }
}

extern "C" void kernel_launch(void* const* d_in, const int* in_sizes, int n_in,
                              void* d_out, int out_size, void* d_ws, size_t ws_size,
                              hipStream_t stream) {
    const float* x    = (const float*)d_in[0];
    const float* ln1g = (const float*)d_in[1];
    const float* ln1b = (const float*)d_in[2];
    const float* Wqkv = (const float*)d_in[3];
    const float* bqkv = (const float*)d_in[4];
    const float* Wo   = (const float*)d_in[5];
    const float* bo   = (const float*)d_in[6];
    const float* ln2g = (const float*)d_in[7];
    const float* ln2b = (const float*)d_in[8];
    const float* Wfc  = (const float*)d_in[9];
    const float* bfc  = (const float*)d_in[10];
    const float* Wpr  = (const float*)d_in[11];
    const float* bpr  = (const float*)d_in[12];
    float* out = (float*)d_out;

    char* ws = (char*)d_ws;
    size_t off = 0;
    auto alloc = [&](size_t bytes) { void* p = ws + off; off += (bytes + 255) & ~(size_t)255; return p; };
    unsigned short* wqkv_t = (unsigned short*)alloc((size_t)3072 * 1024 * 2);
    unsigned short* wo_t   = (unsigned short*)alloc((size_t)1024 * 1024 * 2);
    unsigned short* wfc_t  = (unsigned short*)alloc((size_t)4096 * 1024 * 2);
    unsigned short* wpr_t  = (unsigned short*)alloc((size_t)1024 * 4096 * 2);
    unsigned short* h1     = (unsigned short*)alloc((size_t)MTOK * Cz * 2);
    unsigned short* qbuf   = (unsigned short*)alloc((size_t)MTOK * Cz * 2);
    unsigned short* kbuf   = (unsigned short*)alloc((size_t)MTOK * Cz * 2);
    unsigned short* vbuf   = (unsigned short*)alloc((size_t)MTOK * Cz * 2);   // vt [B,H,D,T]
    unsigned short* ybuf   = (unsigned short*)alloc((size_t)MTOK * Cz * 2);
    float*          x1     = (float*)alloc((size_t)MTOK * Cz * 4);
    unsigned short* h2     = (unsigned short*)alloc((size_t)MTOK * Cz * 2);
    unsigned short* fbuf   = (unsigned short*)alloc((size_t)MTOK * 4096 * 2);
    unsigned short* vtmp   = fbuf;   // disjoint lifetime

    transpose_wf<<<dim3(3072 / 16, 1024 / 128), 256, 0, stream>>>(Wqkv, wqkv_t, 1024, 3072);
    transpose_wf<<<dim3(1024 / 16, 1024 / 128), 256, 0, stream>>>(Wo, wo_t, 1024, 1024);
    transpose_wf<<<dim3(4096 / 16, 1024 / 128), 256, 0, stream>>>(Wfc, wfc_t, 1024, 4096);
    transpose_wf<<<dim3(1024 / 16, 4096 / 128), 256, 0, stream>>>(Wpr, wpr_t, 4096, 1024);

    ln_kernel<<<MTOK, 256, 0, stream>>>(x, ln1g, ln1b, h1);
    // QKV: 128m x 12n = 1536 blocks (Q written pre-scaled by ATT_SC)
    gemm_rp<MODE_QKV><<<1536, 256, 0, stream>>>(h1, wqkv_t, 1024, 3072, bqkv,
                                                nullptr, nullptr, nullptr, qbuf, kbuf, vtmp);
    transpose_v<<<dim3(64, 32), 256, 0, stream>>>(vtmp, vbuf);
    attn_kernel<<<1024, 256, 0, stream>>>(qbuf, kbuf, vbuf, ybuf);
    // O-proj: 128m x 4n = 512 blocks
    gemm_rp<MODE_RESID><<<512, 256, 0, stream>>>(ybuf, wo_t, 1024, 1024, bo,
                                                 x1, nullptr, x, nullptr, nullptr, nullptr);
    ln_kernel<<<MTOK, 256, 0, stream>>>(x1, ln2g, ln2b, h2);
    // FC: 128m x 16n = 2048 blocks
    gemm_rp<MODE_GELU><<<2048, 256, 0, stream>>>(h2, wfc_t, 1024, 4096, bfc,
                                                 nullptr, fbuf, nullptr, nullptr, nullptr, nullptr);
    // PR: K=4096, 128m x 4n = 512 blocks
    gemm_rp<MODE_RESID><<<512, 256, 0, stream>>>(fbuf, wpr_t, 4096, 1024, bpr,
                                                 out, nullptr, x1, nullptr, nullptr, nullptr);
}

// Round 11
// 485.540 us; speedup vs baseline: 1.0382x; 1.0382x over previous
//
#include <hip/hip_runtime.h>
#include <math.h>
#include <stdint.h>

#define Bz 4
#define Tz 2048
#define Cz 1024
#define Hz 16
#define Dz 64
#define MTOK (Bz*Tz)   // 8192
#define ATT_SC 0.18033688011112042f   // 0.125 * log2(e) — folded into Q at QKV epilogue

typedef __attribute__((ext_vector_type(8))) short short8;
typedef __attribute__((ext_vector_type(4))) short short4v;
typedef __attribute__((ext_vector_type(4))) float f32x4;

typedef unsigned int u32_g __attribute__((address_space(1)));
typedef unsigned int u32_l __attribute__((address_space(3)));

__device__ __forceinline__ unsigned short f2bf(float f) {
    unsigned int u = __float_as_uint(f);
    u += 0x7fffu + ((u >> 16) & 1u);
    return (unsigned short)(u >> 16);
}
__device__ __forceinline__ float bf2f(unsigned short h) {
    return __uint_as_float((unsigned int)h << 16);
}

__device__ __forceinline__ void async_cp16(const unsigned short* g, unsigned short* l) {
    __builtin_amdgcn_global_load_lds((const u32_g*)g, (u32_l*)l, 16, 0, 0);
}

#define BARX() asm volatile("s_barrier" ::: "memory")
#define VMCM(n) asm volatile("s_waitcnt vmcnt(" #n ")" ::: "memory")
#define LGKMC(n) do { asm volatile("s_waitcnt lgkmcnt(" #n ")" ::: "memory"); \
                      __builtin_amdgcn_sched_barrier(0); } while (0)

// ---- weight prep: W[K][N] f32 -> Bf fragment-ordered bf16 ----------------------
__global__ void transpose_wf(const float* __restrict__ W, unsigned short* __restrict__ Bf,
                             int K, int N) {
    const int nf = blockIdx.x;
    const int k0 = blockIdx.y * 128;
    const int tid = threadIdx.x;          // 256
    const int ktl = tid >> 6, lane = tid & 63;
    const int col = nf * 16 + (lane & 15);
    const int kk = k0 + ktl * 32 + (lane >> 4) * 8;
    const int KT = K >> 5;
    short8 o;
    #pragma unroll
    for (int j = 0; j < 8; j++)
        o[j] = (short)f2bf(W[(size_t)(kk + j) * N + col]);
    *(short8*)&Bf[(((size_t)nf * KT + (k0 >> 5) + ktl) * 64 + lane) * 8] = o;
}

// ---------------- V transpose: vtmp[B*H][T][D] -> vt[B*H][D][T] -----------------
__global__ void transpose_v(const unsigned short* __restrict__ in, unsigned short* __restrict__ out) {
    __shared__ unsigned short tile[64][68];
    const int bh = blockIdx.x;
    const int t0 = blockIdx.y * 64;
    const int tid = threadIdx.x;
    const int r4 = tid >> 4;
    const int c4 = tid & 15;
    #pragma unroll
    for (int p = 0; p < 4; p++) {
        const int r = p * 16 + r4;
        *(short4v*)&tile[r][c4 * 4] =
            *(const short4v*)&in[((size_t)bh * Tz + t0 + r) * Dz + c4 * 4];
    }
    __syncthreads();
    #pragma unroll
    for (int p = 0; p < 4; p++) {
        const int d = p * 16 + r4;
        short4v o;
        #pragma unroll
        for (int j = 0; j < 4; j++) o[j] = tile[c4 * 4 + j][d];
        *(short4v*)&out[((size_t)bh * Dz + d) * Tz + t0 + c4 * 4] = o;
    }
}

// ---------------- layernorm: fp32 in -> bf16 out ----------------
__global__ void ln_kernel(const float* __restrict__ x, const float* __restrict__ g,
                          const float* __restrict__ bb, unsigned short* __restrict__ out) {
    int tok = blockIdx.x, tid = threadIdx.x;
    const float4 v = ((const float4*)(x + (size_t)tok * Cz))[tid];
    float s = v.x + v.y + v.z + v.w;
    float sq = v.x * v.x + v.y * v.y + v.z * v.z + v.w * v.w;
    #pragma unroll
    for (int m = 1; m < 64; m <<= 1) { s += __shfl_xor(s, m); sq += __shfl_xor(sq, m); }
    __shared__ float red[8];
    int lane = tid & 63, wid = tid >> 6;
    if (!lane) { red[wid] = s; red[4 + wid] = sq; }
    __syncthreads();
    s = red[0] + red[1] + red[2] + red[3];
    sq = red[4] + red[5] + red[6] + red[7];
    float mu = s * (1.0f / Cz);
    float var = sq * (1.0f / Cz) - mu * mu;
    float rs = rsqrtf(var + 1e-5f);
    float4 gv = ((const float4*)g)[tid];
    float4 bv = ((const float4*)bb)[tid];
    short4v o;
    o[0] = f2bf((v.x - mu) * rs * gv.x + bv.x);
    o[1] = f2bf((v.y - mu) * rs * gv.y + bv.y);
    o[2] = f2bf((v.z - mu) * rs * gv.z + bv.z);
    o[3] = f2bf((v.w - mu) * rs * gv.w + bv.w);
    *(short4v*)(out + (size_t)tok * Cz + tid * 4) = o;
}

#define MODE_QKV 0
#define MODE_RESID 1
#define MODE_GELU 2

// ========== register-pipelined GEMM: BM=64 x BN=256, BK=64, 256 thr =============
// Amortization experiment: 32 MFMA/body (was 16), bodies halve. Same gemm_rp
// family: 4 LDS slots x 8KB (two 4KB k-subslots), stage depth 3, B direct-to-VGPR
// lookahead 1 body, inline-asm ds_read double sets (afP/afQ per kslot),
// LGKMC(8) waits only previous body's reads, VMCM(10) steady (retires
// [S(t+2), B(t)] exactly before B(t)'s MFMAs). Tails: VMCM(8) when STG absent,
// VMCM(0) last body. Publication: per-wave VMCM precedes the body barrier, so
// after barrier all waves' stages for slots read next body have landed.
template <int MODE>
__launch_bounds__(256)
__global__ void gemm_rp(const unsigned short* __restrict__ A, const unsigned short* __restrict__ Bf,
                        int K, int N, const float* __restrict__ bias,
                        float* __restrict__ outf, unsigned short* __restrict__ outb,
                        const float* __restrict__ resid,
                        unsigned short* __restrict__ qo, unsigned short* __restrict__ ko,
                        unsigned short* __restrict__ vo) {
    __shared__ __align__(16) unsigned short LDS[4 * 4096];   // 32 KiB
    const int tid = threadIdx.x;
    const int lane = tid & 63;
    const int gn = tid >> 6;               // wave = n-group 0..3
    const int quad = lane >> 4, l15 = lane & 15;
    const int id = blockIdx.x;
    const int rr = id >> 3;
    const int m0 = ((id & 7) * 16 + (rr & 15)) * 64;  // same-m across n -> same XCD
    const int n0 = (rr >> 4) * 256;
    const int NT = K >> 6;                 // BK=64 tiles
    const int KT = K >> 5;                 // B-frag kt granularity stays 32

    // A staging: thread -> row tid/4, phys 16B-seg tid&3, source col pre-swizzled;
    // two cp16 per body: ks0 at slot+0, ks1 (+32 global cols) at slot+2048 shorts.
    const int lseg = (tid & 3) ^ ((tid >> 3) & 3);
    const int srow = tid >> 2;
    const unsigned short* Ag0 = A + (size_t)(m0 + srow) * K + lseg * 8;

    const unsigned ldsA = (unsigned)(uintptr_t)(u32_l*)LDS;
    unsigned offAb[4];
    #pragma unroll
    for (int mi = 0; mi < 4; mi++) {
        const int ra = mi * 16 + l15;
        offAb[mi] = (unsigned)(ra * 64 + ((quad ^ ((ra >> 1) & 3)) << 4));
    }

    const int nfg = (n0 >> 4) + gn * 4;
    const unsigned short* Bp[4];
    #pragma unroll
    for (int ni = 0; ni < 4; ni++)
        Bp[ni] = Bf + ((size_t)(nfg + ni) * KT) * 512 + lane * 8;

    f32x4 acc[4][4] = {};
    short8 afP0[4], afP1[4], afQ0[4], afQ1[4];
    short8 bfP0[4], bfP1[4], bfQ0[4], bfQ1[4];

#define GLBa(bfX) do { _Pragma("unroll") for (int ni = 0; ni < 4; ni++) { \
    asm volatile("global_load_dwordx4 %0, %1, off" \
        : "=&v"(bfX[ni]) : "v"((unsigned long long)(uintptr_t)Bp[ni]) : "memory"); \
    Bp[ni] += 512; } } while (0)
#define STG(tt) do { unsigned short* sp_ = LDS + (((unsigned)(tt)) & 3u) * 4096; \
    const size_t kof_ = (size_t)(tt) * 64; \
    async_cp16(Ag0 + kof_, sp_ + tid * 8); \
    async_cp16(Ag0 + kof_ + 32, sp_ + 2048 + tid * 8); } while (0)
#define RDSa(afX, tt, ks) do { \
    const unsigned sb_ = ldsA + (((unsigned)(tt)) & 3u) * 8192u + (ks) * 4096u; \
    _Pragma("unroll") for (int mi = 0; mi < 4; mi++) \
        asm volatile("ds_read_b128 %0, %1" : "=&v"(afX[mi]) : "v"(sb_ + offAb[mi])); } while (0)
#define MMS(afX, bfX) do { \
    __builtin_amdgcn_s_setprio(1); \
    _Pragma("unroll") for (int mi = 0; mi < 4; mi++) \
        _Pragma("unroll") for (int ni = 0; ni < 4; ni++) \
            acc[mi][ni] = __builtin_amdgcn_mfma_f32_16x16x32_bf16(afX[mi], bfX[ni], acc[mi][ni], 0, 0, 0); \
    __builtin_amdgcn_s_setprio(0); } while (0)

// One body: issue next-body prefetches, counted vmcnt, next-body ds_reads,
// lgkm gate on THIS body's frags (read last body), 32 MFMA.
#define BODY(tt, afC0, afC1, bfC0, bfC1, afN0, afN1, bfN0, bfN1) do { \
    const bool hasS_ = (tt) + 3 < NT, hasB_ = (tt) + 1 < NT; \
    if (hasS_) STG((tt) + 3); \
    if (hasB_) { GLBa(bfN0); GLBa(bfN1); } \
    if (hasS_ && hasB_) { VMCM(10); } else if (hasB_) { VMCM(8); } else { VMCM(0); } \
    if (hasB_) { RDSa(afN0, (tt) + 1, 0); RDSa(afN1, (tt) + 1, 1); LGKMC(8); } \
    else { LGKMC(0); } \
    MMS(afC0, bfC0); \
    MMS(afC1, bfC1); \
    BARX(); } while (0)

    // prologue: stage slots 0..2 (6), B(0) k0+k1 (8) -> 14; VMCM(8) retires all
    // six stages; barrier publishes; pre-read tile-0 frags.
    STG(0); STG(1); STG(2);
    GLBa(bfP0); GLBa(bfP1);
    VMCM(8);
    BARX();
    RDSa(afP0, 0, 0); RDSa(afP1, 0, 1);

    for (int t = 0; t < NT; t += 2) {
        BODY(t,     afP0, afP1, bfP0, bfP1, afQ0, afQ1, bfQ0, bfQ1);
        BODY(t + 1, afQ0, afQ1, bfQ0, bfQ1, afP0, afP1, bfP0, bfP1);
    }
#undef GLBa
#undef STG
#undef RDSa
#undef MMS
#undef BODY

    // epilogue: ni innermost -> full output lines, no write amplification
    float bv[4];
    #pragma unroll
    for (int ni = 0; ni < 4; ni++) bv[ni] = bias[n0 + gn * 64 + ni * 16 + l15];

    if constexpr (MODE == MODE_QKV) {
        const int colb = n0 + gn * 64;
        const int which = colb >> 10;
        const int hh = (colb & 1023) >> 6;
        unsigned short* dst = (which == 0) ? qo : (which == 1) ? ko : vo;
        const float qsc = (which == 0) ? ATT_SC : 1.0f;   // pre-scale Q rows (uniform)
        #pragma unroll
        for (int mi = 0; mi < 4; mi++) {
            #pragma unroll
            for (int r = 0; r < 4; r++) {
                const int row = m0 + mi * 16 + quad * 4 + r;
                const int b_ = row >> 11, tt = row & 2047;
                unsigned short* rp = dst + ((size_t)(b_ * Hz + hh) * Tz + tt) * Dz;
                #pragma unroll
                for (int ni = 0; ni < 4; ni++)
                    rp[ni * 16 + l15] = f2bf((acc[mi][ni][r] + bv[ni]) * qsc);
            }
        }
    } else if constexpr (MODE == MODE_RESID) {
        #pragma unroll
        for (int mi = 0; mi < 4; mi++) {
            #pragma unroll
            for (int r = 0; r < 4; r++) {
                const int row = m0 + mi * 16 + quad * 4 + r;
                float* rp = outf + (size_t)row * N + n0 + gn * 64;
                const float* rr_ = resid + (size_t)row * N + n0 + gn * 64;
                #pragma unroll
                for (int ni = 0; ni < 4; ni++) {
                    const int c = ni * 16 + l15;
                    rp[c] = acc[mi][ni][r] + bv[ni] + rr_[c];
                }
            }
        }
    } else {  // MODE_GELU, tanh-form
        #pragma unroll
        for (int mi = 0; mi < 4; mi++) {
            #pragma unroll
            for (int r = 0; r < 4; r++) {
                const int row = m0 + mi * 16 + quad * 4 + r;
                unsigned short* rp = outb + (size_t)row * N + n0 + gn * 64;
                #pragma unroll
                for (int ni = 0; ni < 4; ni++) {
                    float val = acc[mi][ni][r] + bv[ni];
                    float c = val * (1.0f + 0.044715f * val * val);
                    float e = __expf(1.5957691216057308f * c);
                    rp[ni * 16 + l15] = f2bf(val * e / (1.0f + e));
                }
            }
        }
    }
}

// ---------------- causal flash attention, bf16 MFMA (unchanged from round 10) ---
__launch_bounds__(256)
__global__ void attn_kernel(const unsigned short* __restrict__ qb, const unsigned short* __restrict__ kb,
                            const unsigned short* __restrict__ vt, unsigned short* __restrict__ y) {
    __shared__ __align__(16) unsigned short Klds[2][64 * 64];
    __shared__ __align__(16) unsigned short Vtl[2][64 * 64];
    __shared__ __align__(16) unsigned short Plds[4][16 * 72];
    const int tid = threadIdx.x;
    const int lane = tid & 63, wid = tid >> 6;
    const int quad = lane >> 4, l15 = lane & 15;
    const int bh = blockIdx.x & 63;
    const int qt = 15 - (int)(blockIdx.x >> 6);
    const size_t baseT = (size_t)bh * Tz;
    const size_t vbase = (size_t)bh * Dz;
    const int qb0 = qt * 128;

    const int srow = lane >> 3;
    const int swz = ((lane & 7) ^ srow) * 8;
    const unsigned short* kg0 = kb + (baseT + wid * 8 + srow) * Dz + swz;
    const unsigned short* kg1 = kg0 + (size_t)32 * Dz;
    const unsigned short* vg0 = vt + (vbase + wid * 8 + srow) * Tz + swz;
    const unsigned short* vg1 = vg0 + (size_t)32 * Tz;
    const int lofs = wid * 512 + lane * 8;

#define ASTG(ci_) do { const int s_ = (ci_) & 1; const int kk_ = (ci_) * 64; \
    async_cp16(kg0 + (size_t)kk_ * Dz, &Klds[s_][lofs]); \
    async_cp16(kg1 + (size_t)kk_ * Dz, &Klds[s_][2048 + lofs]); \
    async_cp16(vg0 + kk_, &Vtl[s_][lofs]); \
    async_cp16(vg1 + kk_, &Vtl[s_][2048 + lofs]); } while (0)

    ASTG(0);

    short8 qf[2][2];
    {
        const unsigned short* q0p = qb + (baseT + qb0 + wid * 16 + l15) * Dz + quad * 8;
        qf[0][0] = *(const short8*)q0p;
        qf[0][1] = *(const short8*)(q0p + 32);
        const unsigned short* q1p = q0p + (size_t)64 * Dz;
        qf[1][0] = *(const short8*)q1p;
        qf[1][1] = *(const short8*)(q1p + 32);
    }

    f32x4 o[2][4] = {};
    float lsum[2][4] = {{0.f,0.f,0.f,0.f},{0.f,0.f,0.f,0.f}};

    const int nchunk = 2 * qt + 2;

    for (int ci = 0; ci < nchunk; ci++) {
        VMCM(0);
        BARX();
        if (ci + 1 < nchunk) ASTG(ci + 1);
        const int sl = ci & 1;
        const int k0 = ci * 64;

        #pragma unroll
        for (int t = 0; t < 2; t++) {
            if (t == 0 && ci == nchunk - 1) continue;
            const bool diag = (ci == nchunk - 2 + t);

            f32x4 s[4];
            #pragma unroll
            for (int c = 0; c < 4; c++) {
                const int rk = c * 16 + l15;
                short8 kf0 = *(const short8*)&Klds[sl][rk * 64 + ((quad ^ (rk & 7)) * 8)];
                short8 kf1 = *(const short8*)&Klds[sl][rk * 64 + (((quad + 4) ^ (rk & 7)) * 8)];
                f32x4 z = {};
                z = __builtin_amdgcn_mfma_f32_16x16x32_bf16(qf[t][0], kf0, z, 0, 0, 0);
                s[c] = __builtin_amdgcn_mfma_f32_16x16x32_bf16(qf[t][1], kf1, z, 0, 0, 0);
            }
            const int qr = qb0 + t * 64 + wid * 16 + quad * 4;
            #pragma unroll
            for (int c = 0; c < 4; c++)
                #pragma unroll
                for (int r = 0; r < 4; r++) {
                    float p = exp2f(s[c][r]);
                    if (diag) {
                        int key = k0 + c * 16 + l15;
                        p = (key <= qr + r) ? p : 0.f;
                    }
                    s[c][r] = p;
                    lsum[t][r] += p;
                }
            unsigned short* P = Plds[wid];
            #pragma unroll
            for (int c = 0; c < 4; c++) {
                #pragma unroll
                for (int rp2 = 0; rp2 < 2; rp2++) {
                    unsigned pk;
                    asm("v_cvt_pk_bf16_f32 %0, %1, %2"
                        : "=v"(pk) : "v"(s[c][2 * rp2]), "v"(s[c][2 * rp2 + 1]));
                    P[(quad * 4 + 2 * rp2) * 72 + c * 16 + l15] = (unsigned short)pk;
                    P[(quad * 4 + 2 * rp2 + 1) * 72 + c * 16 + l15] = (unsigned short)(pk >> 16);
                }
            }
            short8 pf0 = *(const short8*)&P[l15 * 72 + quad * 8];
            short8 pf1 = *(const short8*)&P[l15 * 72 + 32 + quad * 8];
            #pragma unroll
            for (int nc = 0; nc < 4; nc++) {
                const int rv = nc * 16 + l15;
                short8 vf0 = *(const short8*)&Vtl[sl][rv * 64 + ((quad ^ (rv & 7)) * 8)];
                short8 vf1 = *(const short8*)&Vtl[sl][rv * 64 + (((quad + 4) ^ (rv & 7)) * 8)];
                o[t][nc] = __builtin_amdgcn_mfma_f32_16x16x32_bf16(pf0, vf0, o[t][nc], 0, 0, 0);
                o[t][nc] = __builtin_amdgcn_mfma_f32_16x16x32_bf16(pf1, vf1, o[t][nc], 0, 0, 0);
            }
        }
    }
#undef ASTG

    const int b_ = bh >> 4, hh = bh & 15;
    #pragma unroll
    for (int t = 0; t < 2; t++)
        #pragma unroll
        for (int r = 0; r < 4; r++) {
            float ls = lsum[t][r];
            #pragma unroll
            for (int m = 1; m < 16; m <<= 1) ls += __shfl_xor(ls, m);
            float inv = 1.0f / ls;
            size_t tok = (size_t)qb0 + t * 64 + wid * 16 + quad * 4 + r;
            unsigned short* yr = y + ((size_t)b_ * Tz + tok) * Cz + hh * Dz;
            #pragma unroll
            for (int nc = 0; nc < 4; nc++)
                yr[nc * 16 + l15] = f2bf(o[t][nc][r] * inv);
        }
}

extern "C" void kernel_launch(void* const* d_in, const int* in_sizes, int n_in,
                              void* d_out, int out_size, void* d_ws, size_t ws_size,
                              hipStream_t stream) {
    const float* x    = (const float*)d_in[0];
    const float* ln1g = (const float*)d_in[1];
    const float* ln1b = (const float*)d_in[2];
    const float* Wqkv = (const float*)d_in[3];
    const float* bqkv = (const float*)d_in[4];
    const float* Wo   = (const float*)d_in[5];
    const float* bo   = (const float*)d_in[6];
    const float* ln2g = (const float*)d_in[7];
    const float* ln2b = (const float*)d_in[8];
    const float* Wfc  = (const float*)d_in[9];
    const float* bfc  = (const float*)d_in[10];
    const float* Wpr  = (const float*)d_in[11];
    const float* bpr  = (const float*)d_in[12];
    float* out = (float*)d_out;

    char* ws = (char*)d_ws;
    size_t off = 0;
    auto alloc = [&](size_t bytes) { void* p = ws + off; off += (bytes + 255) & ~(size_t)255; return p; };
    unsigned short* wqkv_t = (unsigned short*)alloc((size_t)3072 * 1024 * 2);
    unsigned short* wo_t   = (unsigned short*)alloc((size_t)1024 * 1024 * 2);
    unsigned short* wfc_t  = (unsigned short*)alloc((size_t)4096 * 1024 * 2);
    unsigned short* wpr_t  = (unsigned short*)alloc((size_t)1024 * 4096 * 2);
    unsigned short* h1     = (unsigned short*)alloc((size_t)MTOK * Cz * 2);
    unsigned short* qbuf   = (unsigned short*)alloc((size_t)MTOK * Cz * 2);
    unsigned short* kbuf   = (unsigned short*)alloc((size_t)MTOK * Cz * 2);
    unsigned short* vbuf   = (unsigned short*)alloc((size_t)MTOK * Cz * 2);   // vt [B,H,D,T]
    unsigned short* ybuf   = (unsigned short*)alloc((size_t)MTOK * Cz * 2);
    float*          x1     = (float*)alloc((size_t)MTOK * Cz * 4);
    unsigned short* h2     = (unsigned short*)alloc((size_t)MTOK * Cz * 2);
    unsigned short* fbuf   = (unsigned short*)alloc((size_t)MTOK * 4096 * 2);
    unsigned short* vtmp   = fbuf;   // disjoint lifetime

    transpose_wf<<<dim3(3072 / 16, 1024 / 128), 256, 0, stream>>>(Wqkv, wqkv_t, 1024, 3072);
    transpose_wf<<<dim3(1024 / 16, 1024 / 128), 256, 0, stream>>>(Wo, wo_t, 1024, 1024);
    transpose_wf<<<dim3(4096 / 16, 1024 / 128), 256, 0, stream>>>(Wfc, wfc_t, 1024, 4096);
    transpose_wf<<<dim3(1024 / 16, 4096 / 128), 256, 0, stream>>>(Wpr, wpr_t, 4096, 1024);

    ln_kernel<<<MTOK, 256, 0, stream>>>(x, ln1g, ln1b, h1);
    // QKV: 128m x 12n = 1536 blocks (Q written pre-scaled by ATT_SC)
    gemm_rp<MODE_QKV><<<1536, 256, 0, stream>>>(h1, wqkv_t, 1024, 3072, bqkv,
                                                nullptr, nullptr, nullptr, qbuf, kbuf, vtmp);
    transpose_v<<<dim3(64, 32), 256, 0, stream>>>(vtmp, vbuf);
    attn_kernel<<<1024, 256, 0, stream>>>(qbuf, kbuf, vbuf, ybuf);
    // O-proj: 128m x 4n = 512 blocks
    gemm_rp<MODE_RESID><<<512, 256, 0, stream>>>(ybuf, wo_t, 1024, 1024, bo,
                                                 x1, nullptr, x, nullptr, nullptr, nullptr);
    ln_kernel<<<MTOK, 256, 0, stream>>>(x1, ln2g, ln2b, h2);
    // FC: 128m x 16n = 2048 blocks
    gemm_rp<MODE_GELU><<<2048, 256, 0, stream>>>(h2, wfc_t, 1024, 4096, bfc,
                                                 nullptr, fbuf, nullptr, nullptr, nullptr, nullptr);
    // PR: K=4096, 128m x 4n = 512 blocks
    gemm_rp<MODE_RESID><<<512, 256, 0, stream>>>(fbuf, wpr_t, 4096, 1024, bpr,
                                                 out, nullptr, x1, nullptr, nullptr, nullptr);
}